// Round 4
// baseline (856.264 us; speedup 1.0000x reference)
//
#include <hip/hip_runtime.h>

#define NB 262144
#define ZD 510
#define NK 128
#define GAP_THR 2.5f

typedef __attribute__((ext_vector_type(8))) short short8;
typedef __attribute__((ext_vector_type(16))) float f32x16;

// fp32 -> bf16 RNE (data has no NaN)
__device__ inline ushort f2bf(float f) {
    uint x = __builtin_bit_cast(uint, f);
    return (ushort)((x + 0x7fffu + ((x >> 16) & 1u)) >> 16);
}

// --- K0: csq[k] = ||codebook[k]||^2 in fp64 ---
__global__ void csq_kernel(const float* __restrict__ cb, float* __restrict__ csq) {
    int k = threadIdx.x;
    if (k >= NK) return;
    const float* row = cb + (size_t)k * ZD;
    double s = 0.0;
    for (int d = 0; d < ZD; ++d) { double v = (double)row[d]; s = fma(v, v, s); }
    csq[k] = (float)s;
}

// --- KA: bf16 MFMA scores + argmin + gap flag ---
// 512 thr = 8 waves; wave w owns rows blk*512 + w*64 .. +63 (2 row-frags of 32).
// Codebook staged bf16 in LDS, 256-d halves (64KB), chunk-XOR swizzled.
__global__ __launch_bounds__(512, 2) void vq_mfma(
    const float* __restrict__ z, const float* __restrict__ cb,
    const float* __restrict__ csq, int* __restrict__ kf) {
    __shared__ __align__(16) ushort cbl[NK * 256];   // [code][256d] bf16, swizzled: 64KB

    const int tid  = threadIdx.x;
    const int lane = tid & 63;
    const int wv   = tid >> 6;
    const int cmod = lane & 31;
    const int hi   = lane >> 5;
    const int row0 = blockIdx.x * 512 + wv * 64;

    f32x16 acc[2][4];
#pragma unroll
    for (int rf = 0; rf < 2; ++rf)
#pragma unroll
        for (int cf = 0; cf < 4; ++cf)
#pragma unroll
            for (int e = 0; e < 16; ++e) acc[rf][cf][e] = 0.f;

    for (int p = 0; p < 2; ++p) {
        __syncthreads();                 // protect prior pass reads before restage
        // stage codebook d-half: 16384 float2 pairs, coalesced, swizzled LDS writes
#pragma unroll 4
        for (int i = 0; i < 32; ++i) {
            int idx  = tid + (i << 9);
            int code = idx >> 7;
            int dl   = (idx & 127) << 1;         // local d (even)
            int dg   = (p << 8) + dl;
            float2 v = make_float2(0.f, 0.f);
            if (dg + 1 < ZD) v = *(const float2*)(cb + (size_t)code * ZD + dg);
            int chunk = dl >> 3;
            int widx  = code * 256 + ((chunk ^ (code & 7)) << 3) + (dl & 6);
            *(uint*)&cbl[widx] = (uint)f2bf(v.x) | ((uint)f2bf(v.y) << 16);
        }
        __syncthreads();

#pragma unroll 4
        for (int t = 0; t < 16; ++t) {
            const int dbase = (p << 8) + (t << 4) + (hi << 3);
            // A-frags: z global->reg->bf16 (8 consecutive d per lane)
            short8 afr[2];
#pragma unroll
            for (int rf = 0; rf < 2; ++rf) {
                const float* zr = z + (size_t)(row0 + rf * 32 + cmod) * ZD + dbase;
                float2 v0 = *(const float2*)(zr + 0);
                float2 v1 = *(const float2*)(zr + 2);
                float2 v2 = *(const float2*)(zr + 4);
                float2 v3;
                if ((p == 1) && (t == 15) && hi) v3 = make_float2(0.f, 0.f); // d=510,511 pad
                else                             v3 = *(const float2*)(zr + 6);
                union { ushort u[8]; short8 v; } s;
                s.u[0] = f2bf(v0.x); s.u[1] = f2bf(v0.y);
                s.u[2] = f2bf(v1.x); s.u[3] = f2bf(v1.y);
                s.u[4] = f2bf(v2.x); s.u[5] = f2bf(v2.y);
                s.u[6] = f2bf(v3.x); s.u[7] = f2bf(v3.y);
                afr[rf] = s.v;
            }
            // B-frags from LDS (conflict-free via chunk XOR)
            const int chs = (t << 1) | hi;
            const int ba  = cmod * 256 + ((chs ^ (cmod & 7)) << 3);
            short8 bfr[4];
#pragma unroll
            for (int cf = 0; cf < 4; ++cf)
                bfr[cf] = *(const short8*)&cbl[(cf << 13) + ba];
#pragma unroll
            for (int rf = 0; rf < 2; ++rf)
#pragma unroll
                for (int cf = 0; cf < 4; ++cf)
                    acc[rf][cf] = __builtin_amdgcn_mfma_f32_32x32x16_bf16(
                        afr[rf], bfr[cf], acc[rf][cf], 0, 0, 0);
        }
    }

    // epilogue: score = csq - 2*cross; per-row min1/min2 via half-wave butterfly
    float cq[4];
#pragma unroll
    for (int cf = 0; cf < 4; ++cf) cq[cf] = csq[cf * 32 + cmod];

#pragma unroll
    for (int rf = 0; rf < 2; ++rf)
#pragma unroll
        for (int reg = 0; reg < 16; ++reg) {
            float bv = fmaf(-2.f, acc[rf][0][reg], cq[0]);
            int   bk = cmod;
            float m2 = 1e30f;
#pragma unroll
            for (int cf = 1; cf < 4; ++cf) {
                float v = fmaf(-2.f, acc[rf][cf][reg], cq[cf]);
                int  kk = cf * 32 + cmod;
                if (v < bv)      { m2 = bv; bv = v; bk = kk; }
                else if (v < m2) { m2 = v; }
            }
#pragma unroll
            for (int m = 1; m <= 16; m <<= 1) {   // stays within 32-lane half
                float ov  = __shfl_xor(bv, m, 64);
                int   ok  = __shfl_xor(bk, m, 64);
                float om2 = __shfl_xor(m2, m, 64);
                float nm2 = fminf(fmaxf(bv, ov), fminf(m2, om2));
                bool take = (ov < bv) || (ov == bv && ok < bk);
                bv = take ? ov : bv;
                bk = take ? ok : bk;
                m2 = nm2;
            }
            if (cmod == 0) {
                int rloc = rf * 32 + (reg & 3) + ((reg >> 2) << 3) + (hi << 2);
                int enc  = bk;
                if (m2 - bv < GAP_THR) enc |= (int)0x80000000;   // near-tie: repair
                kf[row0 + rloc] = enc;
            }
        }
}

// --- KB: exact fp32 re-score for flagged rows, then gather ---
__global__ __launch_bounds__(256) void repair_gather(
    const float* __restrict__ z, const float* __restrict__ cb,
    const float* __restrict__ csq, const int* __restrict__ kf,
    float* __restrict__ out) {
    __shared__ int km[128];
    const int tid  = threadIdx.x;
    const int row0 = blockIdx.x << 7;
    if (tid < 128) km[tid] = kf[row0 + tid];
    __syncthreads();

    const int wv = tid >> 6, lane = tid & 63;
    for (int i = 0; i < 32; ++i) {
        int enc = km[(wv << 5) + i];
        if (enc >= 0) continue;                       // uniform branch
        int row = row0 + (wv << 5) + i;
        const float* zr = z + (size_t)row * ZD;
        float zv[8];
#pragma unroll
        for (int j = 0; j < 8; ++j) {
            int d = (j << 6) + lane;
            zv[j] = (d < ZD) ? zr[d] : 0.f;
        }
        float bv = 1e30f; int bk = 0;
        for (int c = 0; c < NK; ++c) {
            const float* cr = cb + (size_t)c * ZD;
            float s = 0.f;
#pragma unroll
            for (int j = 0; j < 8; ++j) {
                int d = (j << 6) + lane;
                float cv = (d < ZD) ? cr[d] : 0.f;
                s = fmaf(zv[j], cv, s);
            }
#pragma unroll
            for (int m = 1; m <= 32; m <<= 1) s += __shfl_xor(s, m, 64);
            float sc = fmaf(-2.f, s, csq[c]);
            if (sc < bv) { bv = sc; bk = c; }         // strict < keeps first index
        }
        if (lane == 0) km[(wv << 5) + i] = bk;
    }
    __syncthreads();

    // coalesced gather: 2 rows/pass, 128 threads/row, float2
    const int half = tid >> 7, h = tid & 127;
    for (int rp = 0; rp < 64; ++rp) {
        int row = (rp << 1) + half;
        int k   = km[row] & 127;
        const float2* src = (const float2*)(cb + (size_t)k * ZD);
        float2*       dst = (float2*)(out + (size_t)(row0 + row) * ZD);
        dst[h] = src[h];
        if (h < 127) dst[128 + h] = src[128 + h];
    }
}

extern "C" void kernel_launch(void* const* d_in, const int* in_sizes, int n_in,
                              void* d_out, int out_size, void* d_ws, size_t ws_size,
                              hipStream_t stream) {
    const float* z  = (const float*)d_in[0];
    const float* cb = (const float*)d_in[1];
    float* out = (float*)d_out;
    float* csq = (float*)d_ws;
    int*   kf  = (int*)((char*)d_ws + 1024);

    csq_kernel<<<1, 128, 0, stream>>>(cb, csq);
    vq_mfma<<<NB / 512, 512, 0, stream>>>(z, cb, csq, kf);
    repair_gather<<<NB / 128, 256, 0, stream>>>(z, cb, csq, kf, out);
}

// Round 5
// 445.180 us; speedup vs baseline: 1.9234x; 1.9234x over previous
//
#include <hip/hip_runtime.h>
#include <hip/hip_bf16.h>

#define NB 262144
#define ZD 510
#define NK 128
#define GAP_THR 0.08f
#define CHUNK 64
#define NCHUNK 8

typedef __attribute__((ext_vector_type(8))) short short8;
typedef __attribute__((ext_vector_type(16))) float f32x16;

// split fp32 pair into packed bf16 hi + bf16 lo(residual)
__device__ inline void split2(float2 v, uint& hp, uint& lp) {
    __hip_bfloat16 hx = __float2bfloat16(v.x);
    __hip_bfloat16 hy = __float2bfloat16(v.y);
    float rx = v.x - __bfloat162float(hx);
    float ry = v.y - __bfloat162float(hy);
    __hip_bfloat16 lx = __float2bfloat16(rx);
    __hip_bfloat16 ly = __float2bfloat16(ry);
    hp = (uint)__bfloat16_as_ushort(hx) | ((uint)__bfloat16_as_ushort(hy) << 16);
    lp = (uint)__bfloat16_as_ushort(lx) | ((uint)__bfloat16_as_ushort(ly) << 16);
}

// --- K0: csq[k] = ||cb[k]||^2 in fp64, one block per code ---
__global__ void csq_kernel(const float* __restrict__ cb, float* __restrict__ csq) {
    int k = blockIdx.x, lane = threadIdx.x;
    const float* row = cb + (size_t)k * ZD;
    double s = 0.0;
#pragma unroll
    for (int j = 0; j < 8; ++j) {
        int d = (j << 6) + lane;
        if (d < ZD) { double v = (double)row[d]; s = fma(v, v, s); }
    }
#pragma unroll
    for (int m = 1; m <= 32; m <<= 1) s += __shfl_xor(s, m, 64);
    if (lane == 0) csq[k] = (float)s;
}

// --- K1: fused compensated-bf16 MFMA scores + argmin + flag + gather write ---
// 256 thr = 4 waves; wave w owns 32 rows (acc[4] = 32 rows x 128 codes).
__global__ __launch_bounds__(256, 3) void vq_fused(
    const float* __restrict__ z, const float* __restrict__ cb,
    const float* __restrict__ csq, int* __restrict__ kf, float* __restrict__ out) {
    __shared__ __align__(16) ushort cbh[NK * CHUNK];   // 16 KB hi
    __shared__ __align__(16) ushort cbl[NK * CHUNK];   // 16 KB lo
    __shared__ int km[128];

    const int tid   = threadIdx.x;
    const int lane  = tid & 63;
    const int wv    = tid >> 6;
    const int cmod  = lane & 31;
    const int hi    = lane >> 5;
    const int brow0 = blockIdx.x << 7;          // 128 rows/block
    const int wrow0 = brow0 + (wv << 5);        // wave's 32 rows

    f32x16 acc[4];
#pragma unroll
    for (int cf = 0; cf < 4; ++cf)
#pragma unroll
        for (int e = 0; e < 16; ++e) acc[cf][e] = 0.f;

    const float* zrow = z + (size_t)(wrow0 + cmod) * ZD;

    for (int c = 0; c < NCHUNK; ++c) {
        const int c0 = c * CHUNK;
        __syncthreads();
        // stage cb chunk: 128 codes x 64 d -> hi/lo bf16, XOR-swizzled
#pragma unroll 4
        for (int i = 0; i < 16; ++i) {
            int idx  = tid + (i << 8);
            int code = idx >> 5;
            int dl   = (idx & 31) << 1;
            int dg   = c0 + dl;
            float2 v = (dg < 509) ? *(const float2*)(cb + (size_t)code * ZD + dg)
                                  : make_float2(0.f, 0.f);
            uint hp, lp; split2(v, hp, lp);
            int wa = code * CHUNK + (((dl >> 3) ^ (code & 7)) << 3) + (dl & 7);
            *(uint*)&cbh[wa] = hp;
            *(uint*)&cbl[wa] = lp;
        }
        __syncthreads();

#pragma unroll
        for (int t = 0; t < 4; ++t) {
            const int dbase = c0 + (t << 4) + (hi << 3);
            float2 v0 = *(const float2*)(zrow + dbase);
            float2 v1 = *(const float2*)(zrow + dbase + 2);
            float2 v2 = *(const float2*)(zrow + dbase + 4);
            float2 v3 = (dbase + 6 < ZD) ? *(const float2*)(zrow + dbase + 6)
                                         : make_float2(0.f, 0.f);
            union { uint u[4]; short8 v8; } ah, al;
            split2(v0, ah.u[0], al.u[0]);
            split2(v1, ah.u[1], al.u[1]);
            split2(v2, ah.u[2], al.u[2]);
            split2(v3, ah.u[3], al.u[3]);

            const int sc = (t << 1) | hi;
            const int ba = cmod * CHUNK + ((sc ^ (cmod & 7)) << 3);
#pragma unroll
            for (int cf = 0; cf < 4; ++cf) {
                short8 bh = *(const short8*)&cbh[(cf << 11) + ba];
                short8 bl = *(const short8*)&cbl[(cf << 11) + ba];
                acc[cf] = __builtin_amdgcn_mfma_f32_32x32x16_bf16(al.v8, bh, acc[cf], 0, 0, 0);
                acc[cf] = __builtin_amdgcn_mfma_f32_32x32x16_bf16(ah.v8, bl, acc[cf], 0, 0, 0);
                acc[cf] = __builtin_amdgcn_mfma_f32_32x32x16_bf16(ah.v8, bh, acc[cf], 0, 0, 0);
            }
        }
    }

    // epilogue: score = csq - 2*cross; min1/min2 + argmin per row
    float cq[4];
#pragma unroll
    for (int cf = 0; cf < 4; ++cf) cq[cf] = csq[cf * 32 + cmod];

#pragma unroll
    for (int reg = 0; reg < 16; ++reg) {
        float bv = fmaf(-2.f, acc[0][reg], cq[0]);
        int   bk = cmod;
        float m2 = 1e30f;
#pragma unroll
        for (int cf = 1; cf < 4; ++cf) {
            float v = fmaf(-2.f, acc[cf][reg], cq[cf]);
            int  kk = cf * 32 + cmod;
            if (v < bv)      { m2 = bv; bv = v; bk = kk; }
            else if (v < m2) { m2 = v; }
        }
#pragma unroll
        for (int m = 1; m <= 16; m <<= 1) {
            float ov  = __shfl_xor(bv, m, 64);
            int   ok  = __shfl_xor(bk, m, 64);
            float om2 = __shfl_xor(m2, m, 64);
            float nm2 = fminf(fmaxf(bv, ov), fminf(m2, om2));
            bool take = (ov < bv) || (ov == bv && ok < bk);
            bv = take ? ov : bv;
            bk = take ? ok : bk;
            m2 = nm2;
        }
        if (cmod == 0) {
            int rloc = (reg & 3) + ((reg >> 2) << 3) + (hi << 2);
            int enc  = bk;
            if (m2 - bv < GAP_THR) enc |= (int)0x80000000;
            km[(wv << 5) + rloc] = enc;
            kf[wrow0 + rloc] = enc;
        }
    }
    __syncthreads();

    // gather write: 2 rows/pass, 128 threads/row, float2
    const int half = tid >> 7, h = tid & 127;
    for (int rp = 0; rp < 64; ++rp) {
        int row = (rp << 1) + half;
        int k   = km[row] & 127;
        const float2* src = (const float2*)(cb + (size_t)k * ZD);
        float2*       dst = (float2*)(out + (size_t)(brow0 + row) * ZD);
        dst[h] = src[h];
        if (h < 127) dst[128 + h] = src[128 + h];
    }
}

// --- K2: exact fp32 re-score of flagged rows (thread-per-code), rewrite row ---
__global__ __launch_bounds__(256) void repair(
    const float* __restrict__ z, const float* __restrict__ cb,
    const float* __restrict__ csq, const int* __restrict__ kf,
    float* __restrict__ out) {
    __shared__ float zs[512];
    __shared__ int   kmrow[128];
    __shared__ float wm[2];
    __shared__ int   wk[2];
    __shared__ int   kwin;
    const int tid  = threadIdx.x;
    const int row0 = blockIdx.x << 7;
    if (tid < 128) kmrow[tid] = kf[row0 + tid];
    __syncthreads();

    for (int rl = 0; rl < 128; ++rl) {
        if (kmrow[rl] >= 0) continue;                  // uniform skip
        int row = row0 + rl;
        for (int j = tid; j < 512; j += 256) zs[j] = (j < ZD) ? z[(size_t)row * ZD + j] : 0.f;
        __syncthreads();
        float sc = 1e30f;
        if (tid < NK) {
            const float* cr = cb + (size_t)tid * ZD;
            float s = 0.f;
#pragma unroll 6
            for (int d = 0; d < ZD; ++d) s = fmaf(zs[d], cr[d], s);
            sc = fmaf(-2.f, s, csq[tid]);
        }
        if (tid < 128) {
            float bv = sc; int bk = tid;
#pragma unroll
            for (int m = 1; m <= 32; m <<= 1) {
                float ov = __shfl_xor(bv, m, 64);
                int   ok = __shfl_xor(bk, m, 64);
                bool take = (ov < bv) || (ov == bv && ok < bk);
                bv = take ? ov : bv;
                bk = take ? ok : bk;
            }
            if ((tid & 63) == 0) { wm[tid >> 6] = bv; wk[tid >> 6] = bk; }
        }
        __syncthreads();
        if (tid == 0) {
            bool t1 = (wm[1] < wm[0]) || (wm[1] == wm[0] && wk[1] < wk[0]);
            kwin = t1 ? wk[1] : wk[0];
        }
        __syncthreads();
        int k = kwin;
        const float2* src = (const float2*)(cb + (size_t)k * ZD);
        float2*       dst = (float2*)(out + (size_t)row * ZD);
        if (tid < 255) dst[tid] = src[tid];
        __syncthreads();
    }
}

extern "C" void kernel_launch(void* const* d_in, const int* in_sizes, int n_in,
                              void* d_out, int out_size, void* d_ws, size_t ws_size,
                              hipStream_t stream) {
    const float* z  = (const float*)d_in[0];
    const float* cb = (const float*)d_in[1];
    float* out = (float*)d_out;
    float* csq = (float*)d_ws;
    int*   kf  = (int*)((char*)d_ws + 1024);

    csq_kernel<<<NK, 64, 0, stream>>>(cb, csq);
    vq_fused<<<NB / 128, 256, 0, stream>>>(z, cb, csq, kf, out);
    repair<<<NB / 128, 256, 0, stream>>>(z, cb, csq, kf, out);
}